// Round 5
// baseline (165.929 us; speedup 1.0000x reference)
//
#include <hip/hip_runtime.h>

#define N_PTS   1024
#define IMG_H   128
#define IMG_W   128
#define NPIX    (IMG_H * IMG_W)
#define NEAR    0.01f
#define COV_BLUR 0.3f
#define NCHUNK  32
#define CHUNK_SZ (N_PTS / NCHUNK)     // 32 gaussians per chunk
#define PT_STRIDE 12                  // floats per point record (3 x float4)
#define PXS     4                     // pixels per thread (rows 32 apart)
#define ROWSTEP (NPIX / PXS)          // 4096
#define NSTRIP  (ROWSTEP / 256)       // 16 x-strips, 32 chunk-blocks each

// conic pre-scale: q' = -q/(2 ln2)  ->  exp(-q/2) == exp2(q'), 3-sigma test q' >= 9*s
#define S_SCALE (-0.72134752044448170368f)
#define QLIM    (-6.49212768400033533312f)

// ---------------------------------------------------------------------------
// Kernel 1: fused preprocess + stable depth sort.  16 blocks x 64 threads.
// Each block redundantly computes ALL 1024 depths (3 fma each) into LDS,
// computes the full conic record only for its own 64 points, rank-counts
// from LDS (float4 reads), scatters record to sorted[rank].
// Record: [tz, u, v, ca' | 2cb', cc', a, r | g, b, 0, 0]  (conic pre-scaled)
// Block 0 also zeroes the per-strip combine tickets.
// ---------------------------------------------------------------------------
__global__ __launch_bounds__(64) void k_sortpre(
    const float* __restrict__ coords,
    const float* __restrict__ covs,
    const float* __restrict__ colors,
    const float* __restrict__ alphas,
    const float* __restrict__ Wm,
    const float* __restrict__ Km,
    float* __restrict__ sorted,
    int* __restrict__ tickets)
{
    __shared__ __align__(16) float sdep[N_PTS];
    int tid = threadIdx.x;

    if (blockIdx.x == 0 && tid < NSTRIP) tickets[tid] = 0;

    float R[3][3], tv[3];
    #pragma unroll
    for (int r = 0; r < 3; r++) {
        #pragma unroll
        for (int c = 0; c < 3; c++) R[r][c] = Wm[r * 4 + c];
        tv[r] = Wm[r * 4 + 3];
    }
    float fx = Km[0], fy = Km[4], cx = Km[2], cy = Km[5];

    // all 1024 depths -> LDS (single source of truth for ordering)
    for (int j = tid; j < N_PTS; j += 64) {
        float c0 = coords[3 * j], c1 = coords[3 * j + 1], c2 = coords[3 * j + 2];
        sdep[j] = R[2][0] * c0 + R[2][1] * c1 + R[2][2] * c2 + tv[2];
    }
    __syncthreads();

    // full preprocess for own point
    int i = blockIdx.x * 64 + tid;
    float c0 = coords[3 * i], c1 = coords[3 * i + 1], c2 = coords[3 * i + 2];
    float tx = R[0][0] * c0 + R[0][1] * c1 + R[0][2] * c2 + tv[0];
    float ty = R[1][0] * c0 + R[1][1] * c1 + R[1][2] * c2 + tv[1];
    float tz = sdep[i];                     // identical bits to ranking key

    float invz = 1.0f / fmaxf(tz, NEAR);
    float u = fx * tx * invz + cx;
    float v = fy * ty * invz + cy;
    float J00 = fx * invz;
    float J02 = -fx * tx * invz * invz;
    float J11 = fy * invz;
    float J12 = -fy * ty * invz * invz;

    float S[3][3];
    #pragma unroll
    for (int r = 0; r < 3; r++)
        #pragma unroll
        for (int c = 0; c < 3; c++) S[r][c] = covs[i * 9 + r * 3 + c];

    float M[3][3];
    #pragma unroll
    for (int r = 0; r < 3; r++)
        #pragma unroll
        for (int c = 0; c < 3; c++)
            M[r][c] = R[r][0] * S[0][c] + R[r][1] * S[1][c] + R[r][2] * S[2][c];
    float Sc[3][3];
    #pragma unroll
    for (int r = 0; r < 3; r++)
        #pragma unroll
        for (int c = 0; c < 3; c++)
            Sc[r][c] = M[r][0] * R[c][0] + M[r][1] * R[c][1] + M[r][2] * R[c][2];

    float js0_0 = J00 * Sc[0][0] + J02 * Sc[2][0];
    float js0_1 = J00 * Sc[0][1] + J02 * Sc[2][1];
    float js0_2 = J00 * Sc[0][2] + J02 * Sc[2][2];
    float js1_1 = J11 * Sc[1][1] + J12 * Sc[2][1];
    float js1_2 = J11 * Sc[1][2] + J12 * Sc[2][2];

    float s00 = J00 * js0_0 + J02 * js0_2 + COV_BLUR;
    float s01 = J11 * js0_1 + J12 * js0_2;
    float s11 = J11 * js1_1 + J12 * js1_2 + COV_BLUR;

    float det = s00 * s11 - s01 * s01;
    float invdet = 1.0f / det;
    float caS  = s11 * invdet * S_SCALE;            // pre-scaled conic
    float ccS  = s00 * invdet * S_SCALE;
    float cb2S = -2.0f * s01 * invdet * S_SCALE;

    float a = fminf(fmaxf(alphas[i], 0.0f), 1.0f);
    if (!(tz > NEAR)) a = 0.0f;             // fold 'valid' mask into alpha

    // stable rank count: key = (depth, original index)
    float my = tz;
    int rank = 0;
    const float4* sd4 = (const float4*)sdep;
    #pragma unroll 8
    for (int jj = 0; jj < N_PTS / 4; jj++) {
        float4 d = sd4[jj];
        int j = 4 * jj;
        rank += (d.x < my) || (d.x == my && (j + 0) < i);
        rank += (d.y < my) || (d.y == my && (j + 1) < i);
        rank += (d.z < my) || (d.z == my && (j + 2) < i);
        rank += (d.w < my) || (d.w == my && (j + 3) < i);
    }

    float4* dst = (float4*)(sorted + rank * PT_STRIDE);
    dst[0] = make_float4(tz, u, v, caS);
    dst[1] = make_float4(cb2S, ccS, a, colors[3 * i + 0]);
    dst[2] = make_float4(colors[3 * i + 1], colors[3 * i + 2], 0.0f, 0.0f);
}

// ---------------------------------------------------------------------------
// Kernel 2: per-(pixel-quad, chunk) front-to-back compositing of 32 gaussians
// + fused per-strip combine (split-K "last block" pattern).
// 4 pixels/thread in the same column, rows 32 apart -> dx / ca'*dx^2 / 2cb'*dx
// shared across the quad.  Grid: (16, 32) x 256 -> 512 blocks, 8 waves/CU.
// The block taking the last ticket of its x-strip folds the strip's 32
// partials in depth order and writes the fp32 CHW output.
// ---------------------------------------------------------------------------
__global__ __launch_bounds__(256) void k_composite(
    const float* __restrict__ sorted,
    float* __restrict__ partials,
    int* __restrict__ tickets,
    float* __restrict__ out)
{
    int chunk = blockIdx.y;
    int strip = blockIdx.x;
    int pix = strip * 256 + threadIdx.x;           // 0..4095: rows 0..31

    __shared__ float4 sg[CHUNK_SZ * 3];            // 1.5 KB
    const float4* src = (const float4*)sorted + chunk * CHUNK_SZ * 3;
    if (threadIdx.x < CHUNK_SZ * 3) sg[threadIdx.x] = src[threadIdx.x];
    __syncthreads();

    float px  = (float)(pix & (IMG_W - 1)) + 0.5f;
    float py0 = (float)(pix >> 7) + 0.5f;

    float T[PXS], cr[PXS], cg[PXS], cb[PXS];
    #pragma unroll
    for (int s = 0; s < PXS; s++) { T[s] = 1.0f; cr[s] = cg[s] = cb[s] = 0.0f; }

    #pragma unroll 4
    for (int k = 0; k < CHUNK_SZ; k++) {
        float4 A = sg[3 * k + 0];   // tz, u, v, ca'
        float4 B = sg[3 * k + 1];   // 2cb', cc', a, r
        float4 C = sg[3 * k + 2];   // g, b, -, -
        float dx    = px - A.y;
        float cadxx = (A.w * dx) * dx;
        float cb2dx = B.x * dx;
        #pragma unroll
        for (int s = 0; s < PXS; s++) {
            float dy  = py0 + 32.0f * s - A.z;
            float inr = fmaf(B.y, dy, cb2dx);      // cc'*dy + 2cb'*dx
            float qq  = fmaf(dy, inr, cadxx);      // -q/(2 ln2), <= 0
            float e   = exp2f(qq);                 // exp(-q/2), bare v_exp_f32
            float apx = fminf(B.z * e, 0.999f);
            apx = (qq >= QLIM) ? apx : 0.0f;       // 3-sigma cutoff
            float w = T[s] * apx;
            cr[s] = fmaf(w, B.w, cr[s]);
            cg[s] = fmaf(w, C.x, cg[s]);
            cb[s] = fmaf(w, C.y, cb[s]);
            T[s]  = fmaf(-apx, T[s], T[s]);
        }
    }

    float4* p4 = (float4*)partials;
    #pragma unroll
    for (int s = 0; s < PXS; s++)
        p4[chunk * NPIX + pix + s * ROWSTEP] = make_float4(cr[s], cg[s], cb[s], T[s]);

    // --- fused combine: last chunk-block of this strip folds in depth order
    __threadfence();                               // release partials
    __shared__ int s_ticket;
    if (threadIdx.x == 0)
        s_ticket = atomicAdd(&tickets[strip], 1);
    __syncthreads();
    if (s_ticket != NCHUNK - 1) return;
    __threadfence();                               // acquire others' partials

    float Tc[PXS], r2[PXS], g2[PXS], b2[PXS];
    #pragma unroll
    for (int s = 0; s < PXS; s++) { Tc[s] = 1.0f; r2[s] = g2[s] = b2[s] = 0.0f; }

    #pragma unroll 4
    for (int c = 0; c < NCHUNK; c++) {
        #pragma unroll
        for (int s = 0; s < PXS; s++) {
            float4 p = p4[c * NPIX + pix + s * ROWSTEP];
            r2[s] = fmaf(Tc[s], p.x, r2[s]);
            g2[s] = fmaf(Tc[s], p.y, g2[s]);
            b2[s] = fmaf(Tc[s], p.z, b2[s]);
            Tc[s] *= p.w;
        }
    }
    #pragma unroll
    for (int s = 0; s < PXS; s++) {
        int q = pix + s * ROWSTEP;
        out[0 * NPIX + q] = r2[s];
        out[1 * NPIX + q] = g2[s];
        out[2 * NPIX + q] = b2[s];
    }
}

extern "C" void kernel_launch(void* const* d_in, const int* in_sizes, int n_in,
                              void* d_out, int out_size, void* d_ws, size_t ws_size,
                              hipStream_t stream)
{
    const float* coords = (const float*)d_in[0];
    const float* covs   = (const float*)d_in[1];
    const float* colors = (const float*)d_in[2];
    const float* alphas = (const float*)d_in[3];
    const float* Wm     = (const float*)d_in[4];
    const float* Km     = (const float*)d_in[5];

    float* ws = (float*)d_ws;
    float* sorted   = ws;                          // 1024*12 floats = 48 KB
    float* partials = ws + N_PTS * PT_STRIDE;      // 32*16384*4 floats = 8 MB
    int*   tickets  = (int*)(ws + N_PTS * PT_STRIDE + NCHUNK * NPIX * 4);

    k_sortpre<<<dim3(N_PTS / 64), dim3(64), 0, stream>>>(
        coords, covs, colors, alphas, Wm, Km, sorted, tickets);
    k_composite<<<dim3(NSTRIP, NCHUNK), dim3(256), 0, stream>>>(
        sorted, partials, tickets, (float*)d_out);
}

// Round 6
// 119.860 us; speedup vs baseline: 1.3844x; 1.3844x over previous
//
#include <hip/hip_runtime.h>

#define N_PTS   1024
#define IMG_H   128
#define IMG_W   128
#define NPIX    (IMG_H * IMG_W)
#define NEAR    0.01f
#define COV_BLUR 0.3f
#define NCHUNK  32
#define CHUNK_SZ (N_PTS / NCHUNK)     // 32 gaussians per chunk
#define PT_STRIDE 12                  // floats per point record (3 x float4)
#define PXS     8                     // pixels per thread (rows 16 apart)
#define ROWSTEP (NPIX / PXS)          // 2048
#define CBLK    128                   // composite block size
#define NSTRIP  (ROWSTEP / CBLK)      // 16 strips x 32 chunks = 512 blocks

// conic pre-scale: q' = -q/(2 ln2)  ->  exp(-q/2) == exp2(q'); 3-sigma: q' >= QLIM
#define S_SCALE (-0.72134752044448170368f)
#define QLIM    (-6.49212768400033533312f)

// ---------------------------------------------------------------------------
// Kernel 1: fused preprocess + stable depth sort.  16 blocks x 64 threads.
// Each block redundantly computes ALL 1024 depths (3 fma each) into LDS,
// full conic record only for its own 64 points, rank-counts from LDS
// (float4 reads), scatters record to sorted[rank].
// Record: [tz, u, v, ca' | 2cb', cc', a, r | g, b, 0, 0]  (conic pre-scaled)
// ---------------------------------------------------------------------------
__global__ __launch_bounds__(64) void k_sortpre(
    const float* __restrict__ coords,
    const float* __restrict__ covs,
    const float* __restrict__ colors,
    const float* __restrict__ alphas,
    const float* __restrict__ Wm,
    const float* __restrict__ Km,
    float* __restrict__ sorted)
{
    __shared__ __align__(16) float sdep[N_PTS];
    int tid = threadIdx.x;

    float R[3][3], tv[3];
    #pragma unroll
    for (int r = 0; r < 3; r++) {
        #pragma unroll
        for (int c = 0; c < 3; c++) R[r][c] = Wm[r * 4 + c];
        tv[r] = Wm[r * 4 + 3];
    }
    float fx = Km[0], fy = Km[4], cx = Km[2], cy = Km[5];

    // all 1024 depths -> LDS (single source of truth for ordering)
    for (int j = tid; j < N_PTS; j += 64) {
        float c0 = coords[3 * j], c1 = coords[3 * j + 1], c2 = coords[3 * j + 2];
        sdep[j] = R[2][0] * c0 + R[2][1] * c1 + R[2][2] * c2 + tv[2];
    }
    __syncthreads();

    // full preprocess for own point
    int i = blockIdx.x * 64 + tid;
    float c0 = coords[3 * i], c1 = coords[3 * i + 1], c2 = coords[3 * i + 2];
    float tx = R[0][0] * c0 + R[0][1] * c1 + R[0][2] * c2 + tv[0];
    float ty = R[1][0] * c0 + R[1][1] * c1 + R[1][2] * c2 + tv[1];
    float tz = sdep[i];                     // identical bits to ranking key

    float invz = 1.0f / fmaxf(tz, NEAR);
    float u = fx * tx * invz + cx;
    float v = fy * ty * invz + cy;
    float J00 = fx * invz;
    float J02 = -fx * tx * invz * invz;
    float J11 = fy * invz;
    float J12 = -fy * ty * invz * invz;

    float S[3][3];
    #pragma unroll
    for (int r = 0; r < 3; r++)
        #pragma unroll
        for (int c = 0; c < 3; c++) S[r][c] = covs[i * 9 + r * 3 + c];

    float M[3][3];
    #pragma unroll
    for (int r = 0; r < 3; r++)
        #pragma unroll
        for (int c = 0; c < 3; c++)
            M[r][c] = R[r][0] * S[0][c] + R[r][1] * S[1][c] + R[r][2] * S[2][c];
    float Sc[3][3];
    #pragma unroll
    for (int r = 0; r < 3; r++)
        #pragma unroll
        for (int c = 0; c < 3; c++)
            Sc[r][c] = M[r][0] * R[c][0] + M[r][1] * R[c][1] + M[r][2] * R[c][2];

    float js0_0 = J00 * Sc[0][0] + J02 * Sc[2][0];
    float js0_1 = J00 * Sc[0][1] + J02 * Sc[2][1];
    float js0_2 = J00 * Sc[0][2] + J02 * Sc[2][2];
    float js1_1 = J11 * Sc[1][1] + J12 * Sc[2][1];
    float js1_2 = J11 * Sc[1][2] + J12 * Sc[2][2];

    float s00 = J00 * js0_0 + J02 * js0_2 + COV_BLUR;
    float s01 = J11 * js0_1 + J12 * js0_2;
    float s11 = J11 * js1_1 + J12 * js1_2 + COV_BLUR;

    float det = s00 * s11 - s01 * s01;
    float invdet = 1.0f / det;
    float caS  = s11 * invdet * S_SCALE;            // pre-scaled conic
    float ccS  = s00 * invdet * S_SCALE;
    float cb2S = -2.0f * s01 * invdet * S_SCALE;

    float a = fminf(fmaxf(alphas[i], 0.0f), 1.0f);
    if (!(tz > NEAR)) a = 0.0f;             // fold 'valid' mask into alpha

    // stable rank count: key = (depth, original index)
    float my = tz;
    int rank = 0;
    const float4* sd4 = (const float4*)sdep;
    #pragma unroll 8
    for (int jj = 0; jj < N_PTS / 4; jj++) {
        float4 d = sd4[jj];
        int j = 4 * jj;
        rank += (d.x < my) || (d.x == my && (j + 0) < i);
        rank += (d.y < my) || (d.y == my && (j + 1) < i);
        rank += (d.z < my) || (d.z == my && (j + 2) < i);
        rank += (d.w < my) || (d.w == my && (j + 3) < i);
    }

    float4* dst = (float4*)(sorted + rank * PT_STRIDE);
    dst[0] = make_float4(tz, u, v, caS);
    dst[1] = make_float4(cb2S, ccS, a, colors[3 * i + 0]);
    dst[2] = make_float4(colors[3 * i + 1], colors[3 * i + 2], 0.0f, 0.0f);
}

// ---------------------------------------------------------------------------
// Kernel 2: per-(pixel-octet, chunk) front-to-back compositing of 32
// gaussians.  8 pixels/thread in one column, rows 16 apart: dx / ca'*dx^2 /
// 2cb'*dx shared across 8 rows -> LDS b128 traffic per pixel halved vs PXS=4
// (round-4 composite was LDS-pipe-bound: 8 waves x 32k x 3 ds_read_b128).
// No 0.999 clamp: alphas <= 0.9 and exp2(qq<=0) <= 1, so it never binds.
// Grid: (16 strips, 32 chunks) x 128 -> 512 blocks, 2 blocks/CU, 4 waves/CU.
// ---------------------------------------------------------------------------
__global__ __launch_bounds__(CBLK) void k_composite(
    const float* __restrict__ sorted, float* __restrict__ partials)
{
    int chunk = blockIdx.y;
    int pix = blockIdx.x * CBLK + threadIdx.x;     // 0..2047: cols x rows 0..15

    __shared__ float4 sg[CHUNK_SZ * 3];            // 1.5 KB
    const float4* src = (const float4*)sorted + chunk * CHUNK_SZ * 3;
    if (threadIdx.x < CHUNK_SZ * 3) sg[threadIdx.x] = src[threadIdx.x];
    __syncthreads();

    float px = (float)(pix & (IMG_W - 1)) + 0.5f;
    float pys[PXS];
    #pragma unroll
    for (int s = 0; s < PXS; s++) pys[s] = (float)(pix >> 7) + 0.5f + 16.0f * s;

    float T[PXS], cr[PXS], cg[PXS], cb[PXS];
    #pragma unroll
    for (int s = 0; s < PXS; s++) { T[s] = 1.0f; cr[s] = cg[s] = cb[s] = 0.0f; }

    #pragma unroll 4
    for (int k = 0; k < CHUNK_SZ; k++) {
        float4 A = sg[3 * k + 0];   // tz, u, v, ca'
        float4 B = sg[3 * k + 1];   // 2cb', cc', a, r
        float4 C = sg[3 * k + 2];   // g, b, -, -
        float dx    = px - A.y;
        float cadxx = (A.w * dx) * dx;
        float cb2dx = B.x * dx;
        #pragma unroll
        for (int s = 0; s < PXS; s++) {
            float dy  = pys[s] - A.z;
            float inr = fmaf(B.y, dy, cb2dx);      // cc'*dy + 2cb'*dx
            float qq  = fmaf(dy, inr, cadxx);      // -q/(2 ln2), <= 0
            float e   = exp2f(qq);                 // exp(-q/2)
            float apx = B.z * e;                   // a*g  (clamp never binds)
            apx = (qq >= QLIM) ? apx : 0.0f;       // 3-sigma cutoff
            float w = T[s] * apx;
            cr[s] = fmaf(w, B.w, cr[s]);
            cg[s] = fmaf(w, C.x, cg[s]);
            cb[s] = fmaf(w, C.y, cb[s]);
            T[s]  = fmaf(-apx, T[s], T[s]);
        }
    }

    float4* p4 = (float4*)partials;
    #pragma unroll
    for (int s = 0; s < PXS; s++)
        p4[chunk * NPIX + pix + s * ROWSTEP] = make_float4(cr[s], cg[s], cb[s], T[s]);
}

// ---------------------------------------------------------------------------
// Kernel 3: fold the NCHUNK partials per pixel in depth order, emit fp32 CHW.
// Partial slot I encodes: col = I&127, row = ((I>>7)&15) + 16*(I>>11).
// ---------------------------------------------------------------------------
__global__ __launch_bounds__(128) void k_combine(
    const float* __restrict__ partials, float* __restrict__ out)
{
    int I = blockIdx.x * 128 + threadIdx.x;        // 0..16383
    float T = 1.0f, r = 0.0f, g = 0.0f, b = 0.0f;
    #pragma unroll
    for (int c = 0; c < NCHUNK; c++) {
        float4 p = ((const float4*)partials)[c * NPIX + I];
        r = fmaf(T, p.x, r);
        g = fmaf(T, p.y, g);
        b = fmaf(T, p.z, b);
        T *= p.w;
    }
    int col = I & (IMG_W - 1);
    int row = ((I >> 7) & 15) + 16 * (I >> 11);
    int q = row * IMG_W + col;
    out[0 * NPIX + q] = r;
    out[1 * NPIX + q] = g;
    out[2 * NPIX + q] = b;
}

extern "C" void kernel_launch(void* const* d_in, const int* in_sizes, int n_in,
                              void* d_out, int out_size, void* d_ws, size_t ws_size,
                              hipStream_t stream)
{
    const float* coords = (const float*)d_in[0];
    const float* covs   = (const float*)d_in[1];
    const float* colors = (const float*)d_in[2];
    const float* alphas = (const float*)d_in[3];
    const float* Wm     = (const float*)d_in[4];
    const float* Km     = (const float*)d_in[5];

    float* ws = (float*)d_ws;
    float* sorted   = ws;                          // 1024*12 floats = 48 KB
    float* partials = ws + N_PTS * PT_STRIDE;      // 32*16384*4 floats = 8 MB

    k_sortpre<<<dim3(N_PTS / 64), dim3(64), 0, stream>>>(
        coords, covs, colors, alphas, Wm, Km, sorted);
    k_composite<<<dim3(NSTRIP, NCHUNK), dim3(CBLK), 0, stream>>>(sorted, partials);
    k_combine<<<dim3(NPIX / 128), dim3(128), 0, stream>>>(partials, (float*)d_out);
}

// Round 7
// 110.812 us; speedup vs baseline: 1.4974x; 1.0816x over previous
//
#include <hip/hip_runtime.h>

#define N_PTS   1024
#define IMG_H   128
#define IMG_W   128
#define NPIX    (IMG_H * IMG_W)
#define NEAR    0.01f
#define COV_BLUR 0.3f
#define NCHUNK  32
#define CHUNK_SZ (N_PTS / NCHUNK)     // 32 gaussians per chunk
#define PT_STRIDE 12                  // floats per point record (3 x float4)
#define PXS     4                     // pixels per thread (rows 32 apart)
#define ROWSTEP (NPIX / PXS)          // 4096
#define CBLK    256                   // composite block size (measured best, r4)
#define NSTRIP  (ROWSTEP / CBLK)      // 16 strips x 32 chunks = 512 blocks

// conic pre-scale: q' = -q/(2 ln2)  ->  exp(-q/2) == exp2(q'); 3-sigma: q' >= QLIM
#define S_SCALE (-0.72134752044448170368f)
#define QLIM    (-6.49212768400033533312f)

// ---------------------------------------------------------------------------
// Kernel 1: fused preprocess + stable depth sort.  16 blocks x 64 threads.
// Each block redundantly computes ALL 1024 depths (3 fma each) into LDS,
// full conic record only for its own 64 points, rank-counts from LDS
// (float4 reads), scatters record to sorted[rank].
// Record (alpha folded into exponent):
//   A=[tz, u, v, ca'] B=[2cb', cc', qlim, colR] C=[colG, colB, log2a, 0]
//   where qlim = QLIM + log2(a); apx = exp2(q' + log2 a) needs no a*e mul.
// ---------------------------------------------------------------------------
__global__ __launch_bounds__(64) void k_sortpre(
    const float* __restrict__ coords,
    const float* __restrict__ covs,
    const float* __restrict__ colors,
    const float* __restrict__ alphas,
    const float* __restrict__ Wm,
    const float* __restrict__ Km,
    float* __restrict__ sorted)
{
    __shared__ __align__(16) float sdep[N_PTS];
    int tid = threadIdx.x;

    float R[3][3], tv[3];
    #pragma unroll
    for (int r = 0; r < 3; r++) {
        #pragma unroll
        for (int c = 0; c < 3; c++) R[r][c] = Wm[r * 4 + c];
        tv[r] = Wm[r * 4 + 3];
    }
    float fx = Km[0], fy = Km[4], cx = Km[2], cy = Km[5];

    // all 1024 depths -> LDS (single source of truth for ordering)
    for (int j = tid; j < N_PTS; j += 64) {
        float c0 = coords[3 * j], c1 = coords[3 * j + 1], c2 = coords[3 * j + 2];
        sdep[j] = R[2][0] * c0 + R[2][1] * c1 + R[2][2] * c2 + tv[2];
    }
    __syncthreads();

    // full preprocess for own point
    int i = blockIdx.x * 64 + tid;
    float c0 = coords[3 * i], c1 = coords[3 * i + 1], c2 = coords[3 * i + 2];
    float tx = R[0][0] * c0 + R[0][1] * c1 + R[0][2] * c2 + tv[0];
    float ty = R[1][0] * c0 + R[1][1] * c1 + R[1][2] * c2 + tv[1];
    float tz = sdep[i];                     // identical bits to ranking key

    float invz = 1.0f / fmaxf(tz, NEAR);
    float u = fx * tx * invz + cx;
    float v = fy * ty * invz + cy;
    float J00 = fx * invz;
    float J02 = -fx * tx * invz * invz;
    float J11 = fy * invz;
    float J12 = -fy * ty * invz * invz;

    float S[3][3];
    #pragma unroll
    for (int r = 0; r < 3; r++)
        #pragma unroll
        for (int c = 0; c < 3; c++) S[r][c] = covs[i * 9 + r * 3 + c];

    float M[3][3];
    #pragma unroll
    for (int r = 0; r < 3; r++)
        #pragma unroll
        for (int c = 0; c < 3; c++)
            M[r][c] = R[r][0] * S[0][c] + R[r][1] * S[1][c] + R[r][2] * S[2][c];
    float Sc[3][3];
    #pragma unroll
    for (int r = 0; r < 3; r++)
        #pragma unroll
        for (int c = 0; c < 3; c++)
            Sc[r][c] = M[r][0] * R[c][0] + M[r][1] * R[c][1] + M[r][2] * R[c][2];

    float js0_0 = J00 * Sc[0][0] + J02 * Sc[2][0];
    float js0_1 = J00 * Sc[0][1] + J02 * Sc[2][1];
    float js0_2 = J00 * Sc[0][2] + J02 * Sc[2][2];
    float js1_1 = J11 * Sc[1][1] + J12 * Sc[2][1];
    float js1_2 = J11 * Sc[1][2] + J12 * Sc[2][2];

    float s00 = J00 * js0_0 + J02 * js0_2 + COV_BLUR;
    float s01 = J11 * js0_1 + J12 * js0_2;
    float s11 = J11 * js1_1 + J12 * js1_2 + COV_BLUR;

    float det = s00 * s11 - s01 * s01;
    float invdet = 1.0f / det;
    float caS  = s11 * invdet * S_SCALE;            // pre-scaled conic
    float ccS  = s00 * invdet * S_SCALE;
    float cb2S = -2.0f * s01 * invdet * S_SCALE;

    float a = fminf(fmaxf(alphas[i], 0.0f), 1.0f);
    if (!(tz > NEAR)) a = 0.0f;             // fold 'valid' mask into alpha
    float l2a  = __log2f(a);                // a=0 -> -inf -> exp2 = 0, masked
    float qlim = QLIM + l2a;                // q' + l2a >= qlim  <=>  q <= 9

    // stable rank count: key = (depth, original index)
    float my = tz;
    int rank = 0;
    const float4* sd4 = (const float4*)sdep;
    #pragma unroll 8
    for (int jj = 0; jj < N_PTS / 4; jj++) {
        float4 d = sd4[jj];
        int j = 4 * jj;
        rank += (d.x < my) || (d.x == my && (j + 0) < i);
        rank += (d.y < my) || (d.y == my && (j + 1) < i);
        rank += (d.z < my) || (d.z == my && (j + 2) < i);
        rank += (d.w < my) || (d.w == my && (j + 3) < i);
    }

    float4* dst = (float4*)(sorted + rank * PT_STRIDE);
    dst[0] = make_float4(tz, u, v, caS);
    dst[1] = make_float4(cb2S, ccS, qlim, colors[3 * i + 0]);
    dst[2] = make_float4(colors[3 * i + 1], colors[3 * i + 2], l2a, 0.0f);
}

// ---------------------------------------------------------------------------
// Kernel 2: per-(pixel-quad, chunk) front-to-back compositing of 32 gaussians.
// 4 pixels/thread in one column, rows 32 apart: dx / conic-x terms / log2a
// shared across the quad.  Inner loop is 10 VALU ops per pixel-gaussian pair
// (alpha folded into exp2 exponent; cutoff vs per-gaussian qlim).
// Grid: (16 strips, 32 chunks) x 256 -> 512 blocks, 2/CU, 8 waves/CU
// (measured-best config, round 4).
// ---------------------------------------------------------------------------
__global__ __launch_bounds__(CBLK) void k_composite(
    const float* __restrict__ sorted, float* __restrict__ partials)
{
    int chunk = blockIdx.y;
    int pix = blockIdx.x * CBLK + threadIdx.x;     // 0..4095: cols x rows 0..31

    __shared__ float4 sg[CHUNK_SZ * 3];            // 1.5 KB
    const float4* src = (const float4*)sorted + chunk * CHUNK_SZ * 3;
    if (threadIdx.x < CHUNK_SZ * 3) sg[threadIdx.x] = src[threadIdx.x];
    __syncthreads();

    float px  = (float)(pix & (IMG_W - 1)) + 0.5f;
    float py0 = (float)(pix >> 7) + 0.5f;

    float T[PXS], cr[PXS], cg[PXS], cb[PXS];
    #pragma unroll
    for (int s = 0; s < PXS; s++) { T[s] = 1.0f; cr[s] = cg[s] = cb[s] = 0.0f; }

    #pragma unroll 4
    for (int k = 0; k < CHUNK_SZ; k++) {
        float4 A = sg[3 * k + 0];   // tz, u, v, ca'
        float4 B = sg[3 * k + 1];   // 2cb', cc', qlim, colR
        float4 C = sg[3 * k + 2];   // colG, colB, log2a, 0
        float dx    = px - A.y;
        float cadxx = fmaf(A.w * dx, dx, C.z);     // ca'*dx^2 + log2a
        float cb2dx = B.x * dx;
        #pragma unroll
        for (int s = 0; s < PXS; s++) {
            float dy  = py0 + 32.0f * s - A.z;
            float inr = fmaf(B.y, dy, cb2dx);      // cc'*dy + 2cb'*dx
            float qq  = fmaf(dy, inr, cadxx);      // -q/(2ln2) + log2a
            float e   = exp2f(qq);                 // a * exp(-q/2)
            float apx = (qq >= B.z) ? e : 0.0f;    // 3-sigma cutoff vs qlim
            float w = T[s] * apx;
            cr[s] = fmaf(w, B.w, cr[s]);
            cg[s] = fmaf(w, C.x, cg[s]);
            cb[s] = fmaf(w, C.y, cb[s]);
            T[s]  = fmaf(-apx, T[s], T[s]);
        }
    }

    float4* p4 = (float4*)partials;
    #pragma unroll
    for (int s = 0; s < PXS; s++)
        p4[chunk * NPIX + pix + s * ROWSTEP] = make_float4(cr[s], cg[s], cb[s], T[s]);
}

// ---------------------------------------------------------------------------
// Kernel 3: fold the NCHUNK partials per pixel in depth order, emit fp32 CHW.
// With rows 32 apart and ROWSTEP=4096 the partial slot index IS the image
// pixel index (identity mapping, verified r4): I = pix + 4096*s = row*128+col.
// ---------------------------------------------------------------------------
__global__ __launch_bounds__(128) void k_combine(
    const float* __restrict__ partials, float* __restrict__ out)
{
    int I = blockIdx.x * 128 + threadIdx.x;        // 0..16383
    float T = 1.0f, r = 0.0f, g = 0.0f, b = 0.0f;
    #pragma unroll
    for (int c = 0; c < NCHUNK; c++) {
        float4 p = ((const float4*)partials)[c * NPIX + I];
        r = fmaf(T, p.x, r);
        g = fmaf(T, p.y, g);
        b = fmaf(T, p.z, b);
        T *= p.w;
    }
    out[0 * NPIX + I] = r;
    out[1 * NPIX + I] = g;
    out[2 * NPIX + I] = b;
}

extern "C" void kernel_launch(void* const* d_in, const int* in_sizes, int n_in,
                              void* d_out, int out_size, void* d_ws, size_t ws_size,
                              hipStream_t stream)
{
    const float* coords = (const float*)d_in[0];
    const float* covs   = (const float*)d_in[1];
    const float* colors = (const float*)d_in[2];
    const float* alphas = (const float*)d_in[3];
    const float* Wm     = (const float*)d_in[4];
    const float* Km     = (const float*)d_in[5];

    float* ws = (float*)d_ws;
    float* sorted   = ws;                          // 1024*12 floats = 48 KB
    float* partials = ws + N_PTS * PT_STRIDE;      // 32*16384*4 floats = 8 MB

    k_sortpre<<<dim3(N_PTS / 64), dim3(64), 0, stream>>>(
        coords, covs, colors, alphas, Wm, Km, sorted);
    k_composite<<<dim3(NSTRIP, NCHUNK), dim3(CBLK), 0, stream>>>(sorted, partials);
    k_combine<<<dim3(NPIX / 128), dim3(128), 0, stream>>>(partials, (float*)d_out);
}

// Round 8
// 106.646 us; speedup vs baseline: 1.5559x; 1.0391x over previous
//
#include <hip/hip_runtime.h>

#define N_PTS   1024
#define IMG_H   128
#define IMG_W   128
#define NPIX    (IMG_H * IMG_W)
#define NEAR    0.01f
#define COV_BLUR 0.3f
#define NCHUNK  32
#define CHUNK_SZ (N_PTS / NCHUNK)     // 32 gaussians per chunk
#define PT_STRIDE 12                  // floats per point record (3 x float4)
#define PXS     4                     // pixels per thread (rows 32 apart)
#define ROWSTEP (NPIX / PXS)          // 4096
#define CBLK    256                   // composite block size (measured best, r4)
#define NSTRIP  (ROWSTEP / CBLK)      // 16 strips x 32 chunks = 512 blocks

// conic pre-scale: q' = -q/(2 ln2)  ->  exp(-q/2) == exp2(q'); 3-sigma: q' >= QLIM
#define S_SCALE (-0.72134752044448170368f)
#define QLIM    (-6.49212768400033533312f)

// ---------------------------------------------------------------------------
// Kernel 1: fused preprocess + stable depth sort.  16 blocks x 64 threads.
// Each block redundantly computes ALL 1024 depths (3 fma each) into LDS,
// full conic record only for its own 64 points, rank-counts from LDS
// (float4 reads), scatters record to sorted[rank].
// Record (alpha folded into exponent):
//   A=[tz, u, v, ca'] B=[2cb', cc', qlim, colR] C=[colG, colB, log2a, 0]
//   where qlim = QLIM + log2(a); apx = exp2(q' + log2 a) needs no a*e mul.
// ---------------------------------------------------------------------------
__global__ __launch_bounds__(64) void k_sortpre(
    const float* __restrict__ coords,
    const float* __restrict__ covs,
    const float* __restrict__ colors,
    const float* __restrict__ alphas,
    const float* __restrict__ Wm,
    const float* __restrict__ Km,
    float* __restrict__ sorted)
{
    __shared__ __align__(16) float sdep[N_PTS];
    int tid = threadIdx.x;

    float R[3][3], tv[3];
    #pragma unroll
    for (int r = 0; r < 3; r++) {
        #pragma unroll
        for (int c = 0; c < 3; c++) R[r][c] = Wm[r * 4 + c];
        tv[r] = Wm[r * 4 + 3];
    }
    float fx = Km[0], fy = Km[4], cx = Km[2], cy = Km[5];

    // all 1024 depths -> LDS (single source of truth for ordering)
    for (int j = tid; j < N_PTS; j += 64) {
        float c0 = coords[3 * j], c1 = coords[3 * j + 1], c2 = coords[3 * j + 2];
        sdep[j] = R[2][0] * c0 + R[2][1] * c1 + R[2][2] * c2 + tv[2];
    }
    __syncthreads();

    // full preprocess for own point
    int i = blockIdx.x * 64 + tid;
    float c0 = coords[3 * i], c1 = coords[3 * i + 1], c2 = coords[3 * i + 2];
    float tx = R[0][0] * c0 + R[0][1] * c1 + R[0][2] * c2 + tv[0];
    float ty = R[1][0] * c0 + R[1][1] * c1 + R[1][2] * c2 + tv[1];
    float tz = sdep[i];                     // identical bits to ranking key

    float invz = 1.0f / fmaxf(tz, NEAR);
    float u = fx * tx * invz + cx;
    float v = fy * ty * invz + cy;
    float J00 = fx * invz;
    float J02 = -fx * tx * invz * invz;
    float J11 = fy * invz;
    float J12 = -fy * ty * invz * invz;

    float S[3][3];
    #pragma unroll
    for (int r = 0; r < 3; r++)
        #pragma unroll
        for (int c = 0; c < 3; c++) S[r][c] = covs[i * 9 + r * 3 + c];

    float M[3][3];
    #pragma unroll
    for (int r = 0; r < 3; r++)
        #pragma unroll
        for (int c = 0; c < 3; c++)
            M[r][c] = R[r][0] * S[0][c] + R[r][1] * S[1][c] + R[r][2] * S[2][c];
    float Sc[3][3];
    #pragma unroll
    for (int r = 0; r < 3; r++)
        #pragma unroll
        for (int c = 0; c < 3; c++)
            Sc[r][c] = M[r][0] * R[c][0] + M[r][1] * R[c][1] + M[r][2] * R[c][2];

    float js0_0 = J00 * Sc[0][0] + J02 * Sc[2][0];
    float js0_1 = J00 * Sc[0][1] + J02 * Sc[2][1];
    float js0_2 = J00 * Sc[0][2] + J02 * Sc[2][2];
    float js1_1 = J11 * Sc[1][1] + J12 * Sc[2][1];
    float js1_2 = J11 * Sc[1][2] + J12 * Sc[2][2];

    float s00 = J00 * js0_0 + J02 * js0_2 + COV_BLUR;
    float s01 = J11 * js0_1 + J12 * js0_2;
    float s11 = J11 * js1_1 + J12 * js1_2 + COV_BLUR;

    float det = s00 * s11 - s01 * s01;
    float invdet = 1.0f / det;
    float caS  = s11 * invdet * S_SCALE;            // pre-scaled conic
    float ccS  = s00 * invdet * S_SCALE;
    float cb2S = -2.0f * s01 * invdet * S_SCALE;

    float a = fminf(fmaxf(alphas[i], 0.0f), 1.0f);
    if (!(tz > NEAR)) a = 0.0f;             // fold 'valid' mask into alpha
    float l2a  = __log2f(a);                // a=0 -> -inf -> exp2 = 0, masked
    float qlim = QLIM + l2a;                // q' + l2a >= qlim  <=>  q <= 9

    // stable rank count: key = (depth, original index)
    float my = tz;
    int rank = 0;
    const float4* sd4 = (const float4*)sdep;
    #pragma unroll 16
    for (int jj = 0; jj < N_PTS / 4; jj++) {
        float4 d = sd4[jj];
        int j = 4 * jj;
        rank += (d.x < my) || (d.x == my && (j + 0) < i);
        rank += (d.y < my) || (d.y == my && (j + 1) < i);
        rank += (d.z < my) || (d.z == my && (j + 2) < i);
        rank += (d.w < my) || (d.w == my && (j + 3) < i);
    }

    float4* dst = (float4*)(sorted + rank * PT_STRIDE);
    dst[0] = make_float4(tz, u, v, caS);
    dst[1] = make_float4(cb2S, ccS, qlim, colors[3 * i + 0]);
    dst[2] = make_float4(colors[3 * i + 1], colors[3 * i + 2], l2a, 0.0f);
}

// ---------------------------------------------------------------------------
// Kernel 2: per-(pixel-quad, chunk) front-to-back compositing of 32 gaussians.
// 4 pixels/thread in one column, rows 32 apart: dx / conic-x terms / log2a
// shared across the quad.  k-loop FULLY unrolled so the compiler can hoist
// ds_read_b128s ahead of consuming FMAs (hide LDS latency at 8 waves/CU).
// Grid: (16 strips, 32 chunks) x 256 -> 512 blocks, 2/CU, 8 waves/CU.
// ---------------------------------------------------------------------------
__global__ __launch_bounds__(CBLK) void k_composite(
    const float* __restrict__ sorted, float* __restrict__ partials)
{
    int chunk = blockIdx.y;
    int pix = blockIdx.x * CBLK + threadIdx.x;     // 0..4095: cols x rows 0..31

    __shared__ float4 sg[CHUNK_SZ * 3];            // 1.5 KB
    const float4* src = (const float4*)sorted + chunk * CHUNK_SZ * 3;
    if (threadIdx.x < CHUNK_SZ * 3) sg[threadIdx.x] = src[threadIdx.x];
    __syncthreads();

    float px  = (float)(pix & (IMG_W - 1)) + 0.5f;
    float py0 = (float)(pix >> 7) + 0.5f;

    float T[PXS], cr[PXS], cg[PXS], cb[PXS];
    #pragma unroll
    for (int s = 0; s < PXS; s++) { T[s] = 1.0f; cr[s] = cg[s] = cb[s] = 0.0f; }

    #pragma unroll
    for (int k = 0; k < CHUNK_SZ; k++) {
        float4 A = sg[3 * k + 0];   // tz, u, v, ca'
        float4 B = sg[3 * k + 1];   // 2cb', cc', qlim, colR
        float4 C = sg[3 * k + 2];   // colG, colB, log2a, 0
        float dx    = px - A.y;
        float cadxx = fmaf(A.w * dx, dx, C.z);     // ca'*dx^2 + log2a
        float cb2dx = B.x * dx;
        #pragma unroll
        for (int s = 0; s < PXS; s++) {
            float dy  = py0 + 32.0f * s - A.z;
            float inr = fmaf(B.y, dy, cb2dx);      // cc'*dy + 2cb'*dx
            float qq  = fmaf(dy, inr, cadxx);      // -q/(2ln2) + log2a
            float e   = exp2f(qq);                 // a * exp(-q/2)
            float apx = (qq >= B.z) ? e : 0.0f;    // 3-sigma cutoff vs qlim
            float w = T[s] * apx;
            cr[s] = fmaf(w, B.w, cr[s]);
            cg[s] = fmaf(w, C.x, cg[s]);
            cb[s] = fmaf(w, C.y, cb[s]);
            T[s]  = fmaf(-apx, T[s], T[s]);
        }
    }

    float4* p4 = (float4*)partials;
    #pragma unroll
    for (int s = 0; s < PXS; s++)
        p4[chunk * NPIX + pix + s * ROWSTEP] = make_float4(cr[s], cg[s], cb[s], T[s]);
}

// ---------------------------------------------------------------------------
// Kernel 3: fold the NCHUNK partials per pixel in depth order, emit fp32 CHW.
// With rows 32 apart and ROWSTEP=4096 the partial slot index IS the image
// pixel index (identity mapping, verified r4/r7).
// ---------------------------------------------------------------------------
__global__ __launch_bounds__(256) void k_combine(
    const float* __restrict__ partials, float* __restrict__ out)
{
    int I = blockIdx.x * 256 + threadIdx.x;        // 0..16383, 64 blocks
    float T = 1.0f, r = 0.0f, g = 0.0f, b = 0.0f;
    #pragma unroll
    for (int c = 0; c < NCHUNK; c++) {
        float4 p = ((const float4*)partials)[c * NPIX + I];
        r = fmaf(T, p.x, r);
        g = fmaf(T, p.y, g);
        b = fmaf(T, p.z, b);
        T *= p.w;
    }
    out[0 * NPIX + I] = r;
    out[1 * NPIX + I] = g;
    out[2 * NPIX + I] = b;
}

extern "C" void kernel_launch(void* const* d_in, const int* in_sizes, int n_in,
                              void* d_out, int out_size, void* d_ws, size_t ws_size,
                              hipStream_t stream)
{
    const float* coords = (const float*)d_in[0];
    const float* covs   = (const float*)d_in[1];
    const float* colors = (const float*)d_in[2];
    const float* alphas = (const float*)d_in[3];
    const float* Wm     = (const float*)d_in[4];
    const float* Km     = (const float*)d_in[5];

    float* ws = (float*)d_ws;
    float* sorted   = ws;                          // 1024*12 floats = 48 KB
    float* partials = ws + N_PTS * PT_STRIDE;      // 32*16384*4 floats = 8 MB

    k_sortpre<<<dim3(N_PTS / 64), dim3(64), 0, stream>>>(
        coords, covs, colors, alphas, Wm, Km, sorted);
    k_composite<<<dim3(NSTRIP, NCHUNK), dim3(CBLK), 0, stream>>>(sorted, partials);
    k_combine<<<dim3(NPIX / 256), dim3(256), 0, stream>>>(partials, (float*)d_out);
}